// Round 9
// baseline (576.908 us; speedup 1.0000x reference)
//
#include <hip/hip_runtime.h>
#include <hip/hip_bf16.h>
#include <stdint.h>

#define BB 8
#define TT 168
#define NN 1024
#define BN_ 8192
#define FD_ 16
#define EE 16384

typedef short short8 __attribute__((ext_vector_type(8)));
typedef __bf16 bf16x8 __attribute__((ext_vector_type(8)));
typedef float f32x4 __attribute__((ext_vector_type(4)));

#if __has_builtin(__builtin_amdgcn_exp2f)
#define EXP2(x) __builtin_amdgcn_exp2f(x)
#else
#define EXP2(x) exp2f(x)
#endif
#if __has_builtin(__builtin_amdgcn_rcpf)
#define RCPF(x) __builtin_amdgcn_rcpf(x)
#else
#define RCPF(x) (1.f / (x))
#endif
#define L2E 1.4426950408889634f
#define T2E 2.8853900817779268f

static __device__ __forceinline__ float b2f(ushort s) {
    unsigned u = ((unsigned)s) << 16;
    return __builtin_bit_cast(float, u);
}
static __device__ __forceinline__ float b2f_lo(unsigned u) {   // low bf16 of a u32
    return __builtin_bit_cast(float, u << 16);
}
static __device__ __forceinline__ float b2f_hi(unsigned u) {   // high bf16 of a u32
    return __builtin_bit_cast(float, u & 0xffff0000u);
}
static __device__ __forceinline__ ushort f2b(float f) {      // RNE
    unsigned u = __builtin_bit_cast(unsigned, f);
    unsigned lsb = (u >> 16) & 1u;
    u += 0x7fffu + lsb;
    return (ushort)(u >> 16);
}
static __device__ __forceinline__ ushort f2b_fast(float f) { // round-half-up, 2 ops
    unsigned u = __builtin_bit_cast(unsigned, f);
    return (ushort)((u + 0x8000u) >> 16);
}
static __device__ __forceinline__ f32x4 mfma16(short8 a, short8 b, f32x4 c) {
    return __builtin_amdgcn_mfma_f32_16x16x32_bf16(
        __builtin_bit_cast(bf16x8, a), __builtin_bit_cast(bf16x8, b), c, 0, 0, 0);
}

// ---------------------------------------------------------------------------
// Cast the MFMA-path f32 operands to bf16 in ws.
// ---------------------------------------------------------------------------
#define O_WIH 0
#define O_WHH 8192
#define O_STA 73728
#define O_FCS 335872
#define O_SW  401408
#define O_FW  405504
#define O_UW  406528
#define O_G0W 455680
#define O_G1W 521216
#define O_END 586752

__global__ void cast_kernel(const float* __restrict__ Wih, const float* __restrict__ Whh,
                            const float* __restrict__ sta, const float* __restrict__ fcst,
                            const float* __restrict__ sW, const float* __restrict__ fW,
                            const float* __restrict__ uW, const float* __restrict__ g0W,
                            const float* __restrict__ g1W, ushort* __restrict__ dst) {
    const int i = blockIdx.x * 256 + threadIdx.x;
    if (i >= O_END) return;
    float v;
    if      (i < O_WHH) v = Wih[i - O_WIH];
    else if (i < O_STA) v = Whh[i - O_WHH];
    else if (i < O_FCS) v = sta[i - O_STA];
    else if (i < O_SW)  v = fcst[i - O_FCS];
    else if (i < O_FW)  v = sW[i - O_SW];
    else if (i < O_UW)  v = fW[i - O_FW];
    else if (i < O_G0W) v = uW[i - O_UW];
    else if (i < O_G1W) v = g0W[i - O_G0W];
    else                v = g1W[i - O_G1W];
    dst[i] = f2b(v);
}

// ---------------------------------------------------------------------------
// Graph prep, single block of 1024: degree + wsum (LDS atomics), scan,
// CSR fill (+ CSR-ordered src list + edge->slot map), self-loop edge attr,
// se = sum(We*a_edge) per (hop,head).
// ---------------------------------------------------------------------------
__global__ __launch_bounds__(1024) void prep_kernel(
    const int* __restrict__ ei, const float* __restrict__ ew,
    const float* __restrict__ We0, const float* __restrict__ ae0,
    const float* __restrict__ We1, const float* __restrict__ ae1,
    int* __restrict__ deg0, int* __restrict__ offs, float* __restrict__ loopea,
    int* __restrict__ eidx, int* __restrict__ esrc, int* __restrict__ slotof,
    float* __restrict__ se) {
    __shared__ int degL[1024];
    __shared__ float wsL[1024];
    __shared__ int sc[1024];
    __shared__ float seL[8];
    const int t = threadIdx.x;
    degL[t] = 0; wsL[t] = 0.f;
    if (t < 8) seL[t] = 0.f;
    __syncthreads();
    for (int e = t; e < EE; e += 1024) {
        const int d = ei[EE + e];
        atomicAdd(&degL[d], 1);
        atomicAdd(&wsL[d], ew[e]);
    }
    __syncthreads();
    const int d = degL[t];
    sc[t] = d;
    __syncthreads();
    for (int o = 1; o < 1024; o <<= 1) {
        const int v = (t >= o) ? sc[t - o] : 0;
        __syncthreads();
        sc[t] += v;
        __syncthreads();
    }
    const int excl = sc[t] - d;
    offs[t] = excl;
    deg0[t] = d;
    loopea[t] = wsL[t] / fmaxf((float)d, 1.f);
    degL[t] = excl;           // reuse as cursor
    __syncthreads();
    for (int e = t; e < EE; e += 1024) {
        const int dd = ei[EE + e];
        const int slot = atomicAdd(&degL[dd], 1);
        eidx[slot] = e;
        esrc[slot] = ei[e];   // src in CSR order: gat reads sequentially
        slotof[e] = slot;     // edge_exp writes pexp in CSR order
    }
    // se: 8 groups (hop*4+head) x 128 elems
    const int g = t >> 7, k = t & 127;
    const int head = g & 3;
    const float* W = (g >> 2) ? We1 : We0;
    const float* A = (g >> 2) ? ae1 : ae0;
    atomicAdd(&seL[g], W[head * 128 + k] * A[head * 128 + k]);
    __syncthreads();
    if (t < 8) se[t] = seL[t];
}

// ---------------------------------------------------------------------------
// LSTM: 16 nodes/block, 512 blocks, 4 waves, double-buffered LDS ->
// ONE barrier per step. [r0 form, best measured 300.0 us — FROZEN.
// Closed lines (all measured worse/null): 8-wave occupancy 303, MFMA/trans
// interleave 387 (spills), anti-phase+setprio 308.6, merged-rcp 304.4.]
// ---------------------------------------------------------------------------
__global__ __launch_bounds__(256, 2) void lstm_kernel(
    const float* __restrict__ dyn,    // (B,T,N,16) f32
    const ushort* __restrict__ Wih,   // (512,16) bf16
    const ushort* __restrict__ Whh,   // (512,128) bf16
    const float* __restrict__ bih,
    const float* __restrict__ bhh,
    ushort* __restrict__ zsf)         // (8192,384) bf16, cols 0..127
{
    constexpr int HS = 168;           // [h(128) | x(16) | zero-pad(24)]
    __shared__ ushort hbuf[2][16 * HS];

    const int tid = threadIdx.x;
    const int blk = blockIdx.x;
    const int b = blk >> 6;
    const int n0 = (blk & 63) << 4;
    const int w = tid >> 6, lane = tid & 63, quad = lane >> 4, m = lane & 15;

    short8 Bf[5][4][2];
    float ci[2], cf[2], cg[2], co[2];
#pragma unroll
    for (int jj = 0; jj < 2; jj++) {
        const int u = (2 * w + jj) * 16 + m;
#pragma unroll
        for (int g = 0; g < 4; g++) {
            const int grow = g * 128 + u;
#pragma unroll
            for (int kt = 0; kt < 4; kt++)
                Bf[kt][g][jj] = *(const short8*)(Whh + grow * 128 + kt * 32 + quad * 8);
            if (quad < 2) Bf[4][g][jj] = *(const short8*)(Wih + grow * 16 + quad * 8);
            else          Bf[4][g][jj] = short8{0, 0, 0, 0, 0, 0, 0, 0};
        }
        ci[jj] = -L2E * (bih[u] + bhh[u]);
        cf[jj] = -L2E * (bih[128 + u] + bhh[128 + u]);
        cg[jj] =  T2E * (bih[256 + u] + bhh[256 + u]);
        co[jj] = -L2E * (bih[384 + u] + bhh[384 + u]);
    }

    float c[2][4];
#pragma unroll
    for (int jj = 0; jj < 2; jj++)
#pragma unroll
        for (int r = 0; r < 4; r++) c[jj][r] = 0.f;

    for (int i = tid; i < 2 * 16 * HS; i += 256) ((ushort*)hbuf)[i] = 0;
    __syncthreads();

    const int xn = tid >> 4, xf = tid & 15;
    const size_t xbase = (size_t)b * TT * NN * FD_ + (size_t)(n0 + xn) * FD_ + xf;
    hbuf[0][xn * HS + 128 + xf] = f2b(dyn[xbase]);         // x(0)
    float xv = dyn[xbase + (size_t)NN * FD_];              // x(1)
    __syncthreads();

    for (int t = 0; t < TT; t++) {
        const ushort* rb = hbuf[t & 1];
        ushort* wb = hbuf[(t + 1) & 1];
        if (t + 1 < TT) wb[xn * HS + 128 + xf] = f2b(xv);  // x(t+1) -> write buf
        if (t + 2 < TT) xv = dyn[xbase + (size_t)(t + 2) * NN * FD_];

        f32x4 acc[4][2];
#pragma unroll
        for (int g = 0; g < 4; g++)
#pragma unroll
            for (int jj = 0; jj < 2; jj++) acc[g][jj] = f32x4{0.f, 0.f, 0.f, 0.f};
#pragma unroll
        for (int kt = 0; kt < 5; kt++) {
            short8 a = *(const short8*)&rb[m * HS + kt * 32 + quad * 8];
#pragma unroll
            for (int g = 0; g < 4; g++)
#pragma unroll
                for (int jj = 0; jj < 2; jj++)
                    acc[g][jj] = mfma16(a, Bf[kt][g][jj], acc[g][jj]);
        }

#pragma unroll
        for (int jj = 0; jj < 2; jj++) {
            const int u = (2 * w + jj) * 16 + m;
#pragma unroll
            for (int r = 0; r < 4; r++) {
                const int n = quad * 4 + r;
                const float Di = 1.f + EXP2(fmaf(acc[0][jj][r], -L2E, ci[jj]));
                const float Df = 1.f + EXP2(fmaf(acc[1][jj][r], -L2E, cf[jj]));
                const float Eg = EXP2(fmaf(acc[2][jj][r], T2E, cg[jj]));
                const float Do = 1.f + EXP2(fmaf(acc[3][jj][r], -L2E, co[jj]));
                const float R  = RCPF(Di * (1.f + Eg));
                const float sf = RCPF(Df);
                const float cc = fmaf(sf, c[jj][r], (Eg - 1.f) * R);
                c[jj][r] = cc;
                const float Ec = EXP2(T2E * cc);
                const float h = (Ec - 1.f) * RCPF(Do * (1.f + Ec));
                wb[n * HS + u] = f2b_fast(h);
                if (t == TT - 1) zsf[(size_t)(blk * 16 + n) * 384 + u] = f2b_fast(h);
            }
        }
        __syncthreads();
    }
}

// ---------------------------------------------------------------------------
// Merged s/f GEMM: waves 0..4095 -> s = relu(sta@sW^T+sb) (K=32, cols 128..255),
// waves 4096..8191 -> f = relu(fcst@fW^T+fb) (K=8, cols 256..383).
// ---------------------------------------------------------------------------
__global__ __launch_bounds__(256) void gemm_sf_kernel(
    const ushort* __restrict__ staB, const ushort* __restrict__ sWB,
    const float* __restrict__ sb,
    const ushort* __restrict__ fcsB, const ushort* __restrict__ fWB,
    const float* __restrict__ fb, ushort* __restrict__ zsf) {
    const int tid = threadIdx.x;
    const int lane = tid & 63, quad = lane >> 4, m = lane & 15;
    int wave = blockIdx.x * 4 + (tid >> 6);
    const short8 z8 = short8{0, 0, 0, 0, 0, 0, 0, 0};
    short8 a, bf;
    int r0, c0, ocol;
    const float* bias;
    if (wave < 4096) {
        r0 = (wave >> 3) * 16; c0 = (wave & 7) * 16; ocol = 128; bias = sb;
        a  = *(const short8*)(staB + (size_t)(r0 + m) * 32 + quad * 8);
        bf = *(const short8*)(sWB + (size_t)(c0 + m) * 32 + quad * 8);
    } else {
        wave -= 4096;
        r0 = (wave >> 3) * 16; c0 = (wave & 7) * 16; ocol = 256; bias = fb;
        a  = (quad == 0) ? *(const short8*)(fcsB + (size_t)(r0 + m) * 8) : z8;
        bf = (quad == 0) ? *(const short8*)(fWB + (size_t)(c0 + m) * 8) : z8;
    }
    f32x4 acc = mfma16(a, bf, f32x4{0.f, 0.f, 0.f, 0.f});
    const float bv = bias[c0 + m];
#pragma unroll
    for (int r = 0; r < 4; r++) {
        const int row = r0 + quad * 4 + r;
        zsf[(size_t)row * 384 + ocol + c0 + m] = f2b(fmaxf(acc[r] + bv, 0.f));
    }
}

// ---------------------------------------------------------------------------
// Fusion GEMM: h = relu(zsf @ uW^T + ub), K=384; writes hB (bf16) + hF (f32).
// ---------------------------------------------------------------------------
__global__ __launch_bounds__(256) void gemm_fusion_kernel(
    const ushort* __restrict__ A, const ushort* __restrict__ Bt,
    const float* __restrict__ bias, ushort* __restrict__ hB, float* __restrict__ hF) {
    const int tid = threadIdx.x;
    const int lane = tid & 63, quad = lane >> 4, m = lane & 15;
    const int wave = blockIdx.x * 4 + (tid >> 6);
    const int r0 = (wave >> 3) * 16, c0 = (wave & 7) * 16;
    f32x4 acc = f32x4{0.f, 0.f, 0.f, 0.f};
#pragma unroll
    for (int kt = 0; kt < 12; kt++) {
        const int k = kt * 32 + quad * 8;
        short8 a  = *(const short8*)(A + (size_t)(r0 + m) * 384 + k);
        short8 bf = *(const short8*)(Bt + (size_t)(c0 + m) * 384 + k);
        acc = mfma16(a, bf, acc);
    }
    const int col = c0 + m;
    const float bv = bias[col];
#pragma unroll
    for (int r = 0; r < 4; r++) {
        const int row = r0 + quad * 4 + r;
        const float v = fmaxf(acc[r] + bv, 0.f);
        hB[(size_t)row * 128 + col] = f2b(v);
        hF[(size_t)row * 128 + col] = v;
    }
}

// ---------------------------------------------------------------------------
// Hop GEMM + fused attention scalars. Block = 16 rows; wave w = head w
// (cols w*128..w*128+127). Epilogue: as_/ad_ dot in-register + 16-lane reduce.
// ---------------------------------------------------------------------------
__global__ __launch_bounds__(256) void gemmatt_kernel(
    const ushort* __restrict__ hB, const ushort* __restrict__ W,
    const float* __restrict__ asrc, const float* __restrict__ adst,
    ushort* __restrict__ xl, float* __restrict__ as_, float* __restrict__ ad_) {
    const int tid = threadIdx.x;
    const int lane = tid & 63, quad = lane >> 4, m = lane & 15;
    const int w = tid >> 6;
    const int r0 = blockIdx.x * 16;
    f32x4 acc[8];
#pragma unroll
    for (int ct = 0; ct < 8; ct++) acc[ct] = f32x4{0.f, 0.f, 0.f, 0.f};
#pragma unroll
    for (int kt = 0; kt < 4; kt++) {
        const int k = kt * 32 + quad * 8;
        short8 a = *(const short8*)(hB + (size_t)(r0 + m) * 128 + k);
#pragma unroll
        for (int ct = 0; ct < 8; ct++) {
            short8 bf = *(const short8*)(W + (size_t)(w * 128 + ct * 16 + m) * 128 + k);
            acc[ct] = mfma16(a, bf, acc[ct]);
        }
    }
    float sa[4] = {0.f, 0.f, 0.f, 0.f}, sd[4] = {0.f, 0.f, 0.f, 0.f};
#pragma unroll
    for (int ct = 0; ct < 8; ct++) {
        const int col = w * 128 + ct * 16 + m;
        const float av = asrc[col], dv = adst[col];
#pragma unroll
        for (int r = 0; r < 4; r++) {
            const float v = acc[ct][r];
            xl[(size_t)(r0 + quad * 4 + r) * 512 + col] = f2b(v);
            sa[r] = fmaf(v, av, sa[r]);
            sd[r] = fmaf(v, dv, sd[r]);
        }
    }
#pragma unroll
    for (int o = 1; o < 16; o <<= 1) {
#pragma unroll
        for (int r = 0; r < 4; r++) {
            sa[r] += __shfl_xor(sa[r], o);
            sd[r] += __shfl_xor(sd[r], o);
        }
    }
    if (m == 0) {
#pragma unroll
        for (int r = 0; r < 4; r++) {
            const int node = r0 + quad * 4 + r;
            as_[node * 4 + w] = sa[r];
            ad_[node * 4 + w] = sd[r];
        }
    }
}

// ---------------------------------------------------------------------------
// Per-(batch,edge,head) unnormalized softmax weight: exp(leaky(logit)).
// Written in CSR order (slotof[e]) so gat reads pexp SEQUENTIALLY.
// ---------------------------------------------------------------------------
__global__ __launch_bounds__(256) void edge_exp_kernel(
    const int* __restrict__ ei, const float* __restrict__ ew,
    const float* __restrict__ as_, const float* __restrict__ ad_,
    const int* __restrict__ slotof,
    const float* __restrict__ se4, float* __restrict__ pexp) {
    const int idx = blockIdx.x * 256 + threadIdx.x;   // 131072
    const int b = idx >> 14, e = idx & (EE - 1);
    const int src = b * 1024 + ei[e];
    const int dst = b * 1024 + ei[EE + e];
    const float eaw = ew[e];
    const float4 s4 = *(const float4*)(as_ + src * 4);
    const float4 d4 = *(const float4*)(ad_ + dst * 4);
    float4 p;
    float* pp = (float*)&p;
    const float* s = (const float*)&s4;
    const float* d = (const float*)&d4;
#pragma unroll
    for (int h = 0; h < 4; h++) {
        float a = s[h] + d[h] + eaw * se4[h];
        a = (a < 0.f) ? 0.2f * a : a;
        pp[h] = EXP2(fminf(a, 60.f) * L2E);
    }
    const int slot = slotof[e];
    *(float4*)(pexp + ((size_t)b * EE + slot) * 4) = p;
}

// ---------------------------------------------------------------------------
// Fused GAT hop, 2-way edge slots + CSR-sequential edge metadata:
// per iteration the only DEPENDENT gather is xl[src] — esrc[off+i] (int) and
// pexp[(b*EE+off+i)*4] (float4) are sequential, loop-body-independent, so
// they prefetch ahead. Same iteration order as before -> bit-identical.
// ---------------------------------------------------------------------------
__global__ __launch_bounds__(256) void gat_kernel(
    float* __restrict__ hF, ushort* __restrict__ hB, const ushort* __restrict__ xl,
    const float* __restrict__ as_, const float* __restrict__ ad_,
    const float* __restrict__ pexp,
    const int* __restrict__ esrc, const int* __restrict__ offs,
    const int* __restrict__ deg0, const float* __restrict__ loopea,
    const float* __restrict__ se4, const float* __restrict__ bias,
    const float* __restrict__ lng, const float* __restrict__ lnb, int relu,
    int writeOut, const float* __restrict__ oW, const float* __restrict__ ob,
    float* __restrict__ out) {
    const int lane = threadIdx.x & 63;
    const int half = lane >> 5;                       // edge slot 0/1
    const int c0 = (lane & 31) * 2;                   // cols c0,c0+1,c0+64,c0+65
    const int v = blockIdx.x * 4 + (threadIdx.x >> 6);
    const int b = v >> 10, n = v & 1023;
    const int dg = deg0[n], off = offs[n];

    // self loop -> slot 0 only (slot 1 starts at zero)
    const float lea = loopea[n];
    const float4 s4 = *(const float4*)(as_ + v * 4);
    const float4 d4 = *(const float4*)(ad_ + v * 4);
    const float* sp = (const float*)&s4;
    const float* dp = (const float*)&d4;
    float den[4], num[4][4];
#pragma unroll
    for (int h = 0; h < 4; h++) {
        float a = sp[h] + dp[h] + lea * se4[h];
        a = (a < 0.f) ? 0.2f * a : a;
        float p = EXP2(fminf(a, 60.f) * L2E);
        if (half) p = 0.f;
        den[h] = p;
        const unsigned xa = *(const unsigned*)(xl + (size_t)v * 512 + h * 128 + c0);
        const unsigned xb = *(const unsigned*)(xl + (size_t)v * 512 + h * 128 + 64 + c0);
        num[h][0] = p * b2f_lo(xa);
        num[h][1] = p * b2f_hi(xa);
        num[h][2] = p * b2f_lo(xb);
        num[h][3] = p * b2f_hi(xb);
    }
    for (int i = half; i < dg; i += 2) {
        const int src = b * 1024 + esrc[off + i];
        const float4 p4 = *(const float4*)(pexp + (size_t)(b * EE + off + i) * 4);
        const float* p = (const float*)&p4;
        const ushort* xr = xl + (size_t)src * 512 + c0;
#pragma unroll
        for (int h = 0; h < 4; h++) {
            const unsigned xa = *(const unsigned*)(xr + h * 128);
            const unsigned xb = *(const unsigned*)(xr + h * 128 + 64);
            den[h] += p[h];
            num[h][0] = fmaf(p[h], b2f_lo(xa), num[h][0]);
            num[h][1] = fmaf(p[h], b2f_hi(xa), num[h][1]);
            num[h][2] = fmaf(p[h], b2f_lo(xb), num[h][2]);
            num[h][3] = fmaf(p[h], b2f_hi(xb), num[h][3]);
        }
    }
    // merge edge slots (both halves end with identical sums)
#pragma unroll
    for (int h = 0; h < 4; h++) {
        den[h] += __shfl_xor(den[h], 32);
#pragma unroll
        for (int k = 0; k < 4; k++) num[h][k] += __shfl_xor(num[h][k], 32);
    }

    float o[4] = {0.f, 0.f, 0.f, 0.f};
#pragma unroll
    for (int h = 0; h < 4; h++) {
        const float inv = RCPF(den[h]);
#pragma unroll
        for (int k = 0; k < 4; k++) o[k] = fmaf(num[h][k], inv, o[k]);
    }

    const float2 bva = *(const float2*)(bias + c0);
    const float2 bvb = *(const float2*)(bias + 64 + c0);
    float d0 = o[0] * 0.25f + bva.x;
    float d1 = o[1] * 0.25f + bva.y;
    float d2 = o[2] * 0.25f + bvb.x;
    float d3 = o[3] * 0.25f + bvb.y;
    if (relu) {
        d0 = fmaxf(d0, 0.f); d1 = fmaxf(d1, 0.f);
        d2 = fmaxf(d2, 0.f); d3 = fmaxf(d3, 0.f);
    }
    const float2 hva = *(const float2*)(hF + (size_t)v * 128 + c0);
    const float2 hvb = *(const float2*)(hF + (size_t)v * 128 + 64 + c0);
    const float x0 = hva.x + d0, x1 = hva.y + d1;
    const float x2 = hvb.x + d2, x3 = hvb.y + d3;

    float s = (x0 + x1) + (x2 + x3);
#pragma unroll
    for (int o2 = 32; o2; o2 >>= 1) s += __shfl_xor(s, o2);
    const float mu = s * (1.f / 256.f);               // each col counted twice
    const float e0 = x0 - mu, e1 = x1 - mu, e2 = x2 - mu, e3 = x3 - mu;
    float vs = (e0 * e0 + e1 * e1) + (e2 * e2 + e3 * e3);
#pragma unroll
    for (int o2 = 32; o2; o2 >>= 1) vs += __shfl_xor(vs, o2);
    const float r = rsqrtf(vs * (1.f / 256.f) + 1e-5f);
    const float2 lga = *(const float2*)(lng + c0);
    const float2 lgb = *(const float2*)(lng + 64 + c0);
    const float2 lba = *(const float2*)(lnb + c0);
    const float2 lbb = *(const float2*)(lnb + 64 + c0);
    const float y0 = e0 * r * lga.x + lba.x;
    const float y1 = e1 * r * lga.y + lba.y;
    const float y2 = e2 * r * lgb.x + lbb.x;
    const float y3 = e3 * r * lgb.y + lbb.y;
    if (writeOut) {
        const float2 owa = *(const float2*)(oW + c0);
        const float2 owb = *(const float2*)(oW + 64 + c0);
        float t = (y0 * owa.x + y1 * owa.y) + (y2 * owb.x + y3 * owb.y);
#pragma unroll
        for (int o2 = 32; o2; o2 >>= 1) t += __shfl_xor(t, o2);
        if (lane == 0) out[v] = t * 0.5f + ob[0];     // cols counted twice
    } else if (half == 0) {
        *(float2*)(hF + (size_t)v * 128 + c0) = float2{y0, y1};
        *(float2*)(hF + (size_t)v * 128 + 64 + c0) = float2{y2, y3};
        const unsigned pka = (unsigned)f2b(y0) | ((unsigned)f2b(y1) << 16);
        const unsigned pkb = (unsigned)f2b(y2) | ((unsigned)f2b(y3) << 16);
        *(unsigned*)(hB + (size_t)v * 128 + c0) = pka;
        *(unsigned*)(hB + (size_t)v * 128 + 64 + c0) = pkb;
    }
}

// ---------------------------------------------------------------------------
extern "C" void kernel_launch(void* const* d_in, const int* in_sizes, int n_in,
                              void* d_out, int out_size, void* d_ws, size_t ws_size,
                              hipStream_t stream) {
    const float* dyn  = (const float*)d_in[0];
    const float* fcst = (const float*)d_in[1];
    const float* sta  = (const float*)d_in[2];
    const int*   ei   = (const int*)d_in[3];
    const float* ew   = (const float*)d_in[4];
    const float* lWih = (const float*)d_in[5];
    const float* lWhh = (const float*)d_in[6];
    const float* lbih = (const float*)d_in[7];
    const float* lbhh = (const float*)d_in[8];
    const float* sW = (const float*)d_in[9];
    const float* sb = (const float*)d_in[10];
    const float* fW = (const float*)d_in[11];
    const float* fb = (const float*)d_in[12];
    const float* uW = (const float*)d_in[13];
    const float* ub = (const float*)d_in[14];
    const float* g0W  = (const float*)d_in[15];
    const float* g0as = (const float*)d_in[16];
    const float* g0ad = (const float*)d_in[17];
    const float* g0ae = (const float*)d_in[18];
    const float* g0We = (const float*)d_in[19];
    const float* g0b  = (const float*)d_in[20];
    const float* g1W  = (const float*)d_in[21];
    const float* g1as = (const float*)d_in[22];
    const float* g1ad = (const float*)d_in[23];
    const float* g1ae = (const float*)d_in[24];
    const float* g1We = (const float*)d_in[25];
    const float* g1b  = (const float*)d_in[26];
    const float* ln0g = (const float*)d_in[27];
    const float* ln0b = (const float*)d_in[28];
    const float* ln1g = (const float*)d_in[29];
    const float* ln1b = (const float*)d_in[30];
    const float* oW = (const float*)d_in[31];
    const float* ob = (const float*)d_in[32];

    char* p = (char*)d_ws;
    ushort* castB = (ushort*)p; p += (size_t)O_END * 2 + 512;
    ushort* zsf = (ushort*)p;  p += (size_t)BN_ * 384 * 2;      // pexp overlays (dead after fusion)
    float*  hF  = (float*)p;   p += (size_t)BN_ * 128 * 4;
    ushort* hB  = (ushort*)p;  p += (size_t)BN_ * 128 * 2;
    ushort* xl  = (ushort*)p;  p += (size_t)BN_ * 512 * 2;
    float*  asb = (float*)p;   p += (size_t)BN_ * 4 * 4;
    float*  adb = (float*)p;   p += (size_t)BN_ * 4 * 4;
    int*    deg0   = (int*)p;   p += 4096;
    int*    offs   = (int*)p;   p += 4096;
    float*  loopea = (float*)p; p += 4096;
    int*    eidx   = (int*)p;   p += (size_t)EE * 4;
    int*    esrc   = (int*)p;   p += (size_t)EE * 4;
    int*    slotof = (int*)p;   p += (size_t)EE * 4;
    float*  se     = (float*)p; p += 256;
    float*  pexp   = (float*)zsf;   // 8*16384*4 f32 = 2 MB, zsf dead after fusion

    const ushort* WihB = castB + O_WIH;
    const ushort* WhhB = castB + O_WHH;
    const ushort* staB = castB + O_STA;
    const ushort* fcsB = castB + O_FCS;
    const ushort* sWB  = castB + O_SW;
    const ushort* fWB  = castB + O_FW;
    const ushort* uWB  = castB + O_UW;
    const ushort* g0WB = castB + O_G0W;
    const ushort* g1WB = castB + O_G1W;

    cast_kernel<<<(O_END + 255) / 256, 256, 0, stream>>>(lWih, lWhh, sta, fcst, sW, fW,
                                                         uW, g0W, g1W, castB);
    prep_kernel<<<1, 1024, 0, stream>>>(ei, ew, g0We, g0ae, g1We, g1ae,
                                        deg0, offs, loopea, eidx, esrc, slotof, se);

    lstm_kernel<<<512, 256, 0, stream>>>(dyn, WihB, WhhB, lbih, lbhh, zsf);
    gemm_sf_kernel<<<2048, 256, 0, stream>>>(staB, sWB, sb, fcsB, fWB, fb, zsf);
    gemm_fusion_kernel<<<1024, 256, 0, stream>>>(zsf, uWB, ub, hB, hF);

    // hop 0
    gemmatt_kernel<<<512, 256, 0, stream>>>(hB, g0WB, g0as, g0ad, xl, asb, adb);
    edge_exp_kernel<<<512, 256, 0, stream>>>(ei, ew, asb, adb, slotof, se, pexp);
    gat_kernel<<<2048, 256, 0, stream>>>(hF, hB, xl, asb, adb, pexp, esrc, offs, deg0,
                                         loopea, se, g0b, ln0g, ln0b, 1,
                                         0, oW, ob, (float*)d_out);
    // hop 1
    gemmatt_kernel<<<512, 256, 0, stream>>>(hB, g1WB, g1as, g1ad, xl, asb, adb);
    edge_exp_kernel<<<512, 256, 0, stream>>>(ei, ew, asb, adb, slotof, se + 4, pexp);
    gat_kernel<<<2048, 256, 0, stream>>>(hF, hB, xl, asb, adb, pexp, esrc, offs, deg0,
                                         loopea, se + 4, g1b, ln1g, ln1b, 0,
                                         1, oW, ob, (float*)d_out);
}

// Round 10
// 550.249 us; speedup vs baseline: 1.0484x; 1.0484x over previous
//
#include <hip/hip_runtime.h>
#include <hip/hip_bf16.h>
#include <stdint.h>

#define BB 8
#define TT 168
#define NN 1024
#define BN_ 8192
#define FD_ 16
#define EE 16384

typedef short short8 __attribute__((ext_vector_type(8)));
typedef __bf16 bf16x8 __attribute__((ext_vector_type(8)));
typedef float f32x4 __attribute__((ext_vector_type(4)));

#if __has_builtin(__builtin_amdgcn_exp2f)
#define EXP2(x) __builtin_amdgcn_exp2f(x)
#else
#define EXP2(x) exp2f(x)
#endif
#if __has_builtin(__builtin_amdgcn_rcpf)
#define RCPF(x) __builtin_amdgcn_rcpf(x)
#else
#define RCPF(x) (1.f / (x))
#endif
#define L2E 1.4426950408889634f
#define T2E 2.8853900817779268f

static __device__ __forceinline__ float b2f(ushort s) {
    unsigned u = ((unsigned)s) << 16;
    return __builtin_bit_cast(float, u);
}
static __device__ __forceinline__ float b2f_lo(unsigned u) {   // low bf16 of a u32
    return __builtin_bit_cast(float, u << 16);
}
static __device__ __forceinline__ float b2f_hi(unsigned u) {   // high bf16 of a u32
    return __builtin_bit_cast(float, u & 0xffff0000u);
}
static __device__ __forceinline__ ushort f2b(float f) {      // RNE
    unsigned u = __builtin_bit_cast(unsigned, f);
    unsigned lsb = (u >> 16) & 1u;
    u += 0x7fffu + lsb;
    return (ushort)(u >> 16);
}
static __device__ __forceinline__ ushort f2b_fast(float f) { // round-half-up, 2 ops
    unsigned u = __builtin_bit_cast(unsigned, f);
    return (ushort)((u + 0x8000u) >> 16);
}
static __device__ __forceinline__ f32x4 mfma16(short8 a, short8 b, f32x4 c) {
    return __builtin_amdgcn_mfma_f32_16x16x32_bf16(
        __builtin_bit_cast(bf16x8, a), __builtin_bit_cast(bf16x8, b), c, 0, 0, 0);
}

// ---------------------------------------------------------------------------
// Cast offsets (bf16 staging in ws).
// ---------------------------------------------------------------------------
#define O_WIH 0
#define O_WHH 8192
#define O_STA 73728
#define O_FCS 335872
#define O_SW  401408
#define O_FW  405504
#define O_UW  406528
#define O_G0W 455680
#define O_G1W 521216
#define O_END 586752

// ---------------------------------------------------------------------------
// Merged cast + graph-prep: block 0 (1024 thr) runs prep (degree/wsum LDS
// atomics, scan, CSR fill, self-loop ea, se); blocks 1.. cast f32->bf16.
// Saves one dispatch bubble; paths are independent.
// ---------------------------------------------------------------------------
__global__ __launch_bounds__(1024) void cast_prep_kernel(
    const float* __restrict__ Wih, const float* __restrict__ Whh,
    const float* __restrict__ sta, const float* __restrict__ fcst,
    const float* __restrict__ sW, const float* __restrict__ fW,
    const float* __restrict__ uW, const float* __restrict__ g0W,
    const float* __restrict__ g1W, ushort* __restrict__ dst,
    const int* __restrict__ ei, const float* __restrict__ ew,
    const float* __restrict__ We0, const float* __restrict__ ae0,
    const float* __restrict__ We1, const float* __restrict__ ae1,
    int* __restrict__ deg0, int* __restrict__ offs, float* __restrict__ loopea,
    int* __restrict__ eidx, float* __restrict__ se) {
    if (blockIdx.x != 0) {
        const int i = (blockIdx.x - 1) * 1024 + threadIdx.x;
        if (i >= O_END) return;
        float v;
        if      (i < O_WHH) v = Wih[i - O_WIH];
        else if (i < O_STA) v = Whh[i - O_WHH];
        else if (i < O_FCS) v = sta[i - O_STA];
        else if (i < O_SW)  v = fcst[i - O_FCS];
        else if (i < O_FW)  v = sW[i - O_SW];
        else if (i < O_UW)  v = fW[i - O_FW];
        else if (i < O_G0W) v = uW[i - O_UW];
        else if (i < O_G1W) v = g0W[i - O_G0W];
        else                v = g1W[i - O_G1W];
        dst[i] = f2b(v);
        return;
    }
    __shared__ int degL[1024];
    __shared__ float wsL[1024];
    __shared__ int sc[1024];
    __shared__ float seL[8];
    const int t = threadIdx.x;
    degL[t] = 0; wsL[t] = 0.f;
    if (t < 8) seL[t] = 0.f;
    __syncthreads();
    for (int e = t; e < EE; e += 1024) {
        const int d = ei[EE + e];
        atomicAdd(&degL[d], 1);
        atomicAdd(&wsL[d], ew[e]);
    }
    __syncthreads();
    const int d = degL[t];
    sc[t] = d;
    __syncthreads();
    for (int o = 1; o < 1024; o <<= 1) {
        const int v = (t >= o) ? sc[t - o] : 0;
        __syncthreads();
        sc[t] += v;
        __syncthreads();
    }
    const int excl = sc[t] - d;
    offs[t] = excl;
    deg0[t] = d;
    loopea[t] = wsL[t] / fmaxf((float)d, 1.f);
    degL[t] = excl;           // reuse as cursor
    __syncthreads();
    for (int e = t; e < EE; e += 1024) {
        const int dd = ei[EE + e];
        const int slot = atomicAdd(&degL[dd], 1);
        eidx[slot] = e;
    }
    // se: 8 groups (hop*4+head) x 128 elems
    const int g = t >> 7, k = t & 127;
    const int head = g & 3;
    const float* W = (g >> 2) ? We1 : We0;
    const float* A = (g >> 2) ? ae1 : ae0;
    atomicAdd(&seL[g], W[head * 128 + k] * A[head * 128 + k]);
    __syncthreads();
    if (t < 8) se[t] = seL[t];
}

// ---------------------------------------------------------------------------
// LSTM: 16 nodes/block, 512 blocks, 4 waves, double-buffered LDS ->
// ONE barrier per step. [r0 form, best measured 300.0 us — FROZEN.
// Closed lines (all measured worse/null): 8-wave occupancy 303, MFMA/trans
// interleave 387 (spills), anti-phase+setprio 308.6, merged-rcp 304.4.]
// ---------------------------------------------------------------------------
__global__ __launch_bounds__(256, 2) void lstm_kernel(
    const float* __restrict__ dyn,    // (B,T,N,16) f32
    const ushort* __restrict__ Wih,   // (512,16) bf16
    const ushort* __restrict__ Whh,   // (512,128) bf16
    const float* __restrict__ bih,
    const float* __restrict__ bhh,
    ushort* __restrict__ zsf)         // (8192,384) bf16, cols 0..127
{
    constexpr int HS = 168;           // [h(128) | x(16) | zero-pad(24)]
    __shared__ ushort hbuf[2][16 * HS];

    const int tid = threadIdx.x;
    const int blk = blockIdx.x;
    const int b = blk >> 6;
    const int n0 = (blk & 63) << 4;
    const int w = tid >> 6, lane = tid & 63, quad = lane >> 4, m = lane & 15;

    short8 Bf[5][4][2];
    float ci[2], cf[2], cg[2], co[2];
#pragma unroll
    for (int jj = 0; jj < 2; jj++) {
        const int u = (2 * w + jj) * 16 + m;
#pragma unroll
        for (int g = 0; g < 4; g++) {
            const int grow = g * 128 + u;
#pragma unroll
            for (int kt = 0; kt < 4; kt++)
                Bf[kt][g][jj] = *(const short8*)(Whh + grow * 128 + kt * 32 + quad * 8);
            if (quad < 2) Bf[4][g][jj] = *(const short8*)(Wih + grow * 16 + quad * 8);
            else          Bf[4][g][jj] = short8{0, 0, 0, 0, 0, 0, 0, 0};
        }
        ci[jj] = -L2E * (bih[u] + bhh[u]);
        cf[jj] = -L2E * (bih[128 + u] + bhh[128 + u]);
        cg[jj] =  T2E * (bih[256 + u] + bhh[256 + u]);
        co[jj] = -L2E * (bih[384 + u] + bhh[384 + u]);
    }

    float c[2][4];
#pragma unroll
    for (int jj = 0; jj < 2; jj++)
#pragma unroll
        for (int r = 0; r < 4; r++) c[jj][r] = 0.f;

    for (int i = tid; i < 2 * 16 * HS; i += 256) ((ushort*)hbuf)[i] = 0;
    __syncthreads();

    const int xn = tid >> 4, xf = tid & 15;
    const size_t xbase = (size_t)b * TT * NN * FD_ + (size_t)(n0 + xn) * FD_ + xf;
    hbuf[0][xn * HS + 128 + xf] = f2b(dyn[xbase]);         // x(0)
    float xv = dyn[xbase + (size_t)NN * FD_];              // x(1)
    __syncthreads();

    for (int t = 0; t < TT; t++) {
        const ushort* rb = hbuf[t & 1];
        ushort* wb = hbuf[(t + 1) & 1];
        if (t + 1 < TT) wb[xn * HS + 128 + xf] = f2b(xv);  // x(t+1) -> write buf
        if (t + 2 < TT) xv = dyn[xbase + (size_t)(t + 2) * NN * FD_];

        f32x4 acc[4][2];
#pragma unroll
        for (int g = 0; g < 4; g++)
#pragma unroll
            for (int jj = 0; jj < 2; jj++) acc[g][jj] = f32x4{0.f, 0.f, 0.f, 0.f};
#pragma unroll
        for (int kt = 0; kt < 5; kt++) {
            short8 a = *(const short8*)&rb[m * HS + kt * 32 + quad * 8];
#pragma unroll
            for (int g = 0; g < 4; g++)
#pragma unroll
                for (int jj = 0; jj < 2; jj++)
                    acc[g][jj] = mfma16(a, Bf[kt][g][jj], acc[g][jj]);
        }

#pragma unroll
        for (int jj = 0; jj < 2; jj++) {
            const int u = (2 * w + jj) * 16 + m;
#pragma unroll
            for (int r = 0; r < 4; r++) {
                const int n = quad * 4 + r;
                const float Di = 1.f + EXP2(fmaf(acc[0][jj][r], -L2E, ci[jj]));
                const float Df = 1.f + EXP2(fmaf(acc[1][jj][r], -L2E, cf[jj]));
                const float Eg = EXP2(fmaf(acc[2][jj][r], T2E, cg[jj]));
                const float Do = 1.f + EXP2(fmaf(acc[3][jj][r], -L2E, co[jj]));
                const float R  = RCPF(Di * (1.f + Eg));
                const float sf = RCPF(Df);
                const float cc = fmaf(sf, c[jj][r], (Eg - 1.f) * R);
                c[jj][r] = cc;
                const float Ec = EXP2(T2E * cc);
                const float h = (Ec - 1.f) * RCPF(Do * (1.f + Ec));
                wb[n * HS + u] = f2b_fast(h);
                if (t == TT - 1) zsf[(size_t)(blk * 16 + n) * 384 + u] = f2b_fast(h);
            }
        }
        __syncthreads();
    }
}

// ---------------------------------------------------------------------------
// Fused s/f + fusion GEMM: one 512-thr block per 16 rows. Wave w computes
// s-tile (K=32) and f-tile (K=8) at cols w*16, stores bf16 via the SAME
// f2b(relu(+bias)) path into padded LDS [16][264] (2-way bank conflicts),
// barrier, then fusion h = relu(zsf@uW^T+ub) K=384 reading k<128 from
// global zsf (lstm cols) and k>=128 from LDS. Bit-identical numerics;
// removes the gemm_sf launch and the 4MB zsf round-trip for s/f.
// ---------------------------------------------------------------------------
__global__ __launch_bounds__(512) void gemm_fusion_kernel(
    const ushort* __restrict__ staB, const ushort* __restrict__ sWB,
    const float* __restrict__ sb,
    const ushort* __restrict__ fcsB, const ushort* __restrict__ fWB,
    const float* __restrict__ fb,
    const ushort* __restrict__ zsfA, const ushort* __restrict__ Bt,
    const float* __restrict__ bias, ushort* __restrict__ hB, float* __restrict__ hF) {
    constexpr int LP = 264;                    // padded LDS row (bf16)
    __shared__ ushort sf[16][LP];
    const int tid = threadIdx.x;
    const int lane = tid & 63, quad = lane >> 4, m = lane & 15;
    const int w = tid >> 6;
    const int r0 = blockIdx.x * 16, c0 = w * 16;
    const short8 z8 = short8{0, 0, 0, 0, 0, 0, 0, 0};

    // s: K=32
    short8 a = *(const short8*)(staB + (size_t)(r0 + m) * 32 + quad * 8);
    short8 bf = *(const short8*)(sWB + (size_t)(c0 + m) * 32 + quad * 8);
    f32x4 acc_s = mfma16(a, bf, f32x4{0.f, 0.f, 0.f, 0.f});
    // f: K=8 (quad 0 only)
    a  = (quad == 0) ? *(const short8*)(fcsB + (size_t)(r0 + m) * 8) : z8;
    bf = (quad == 0) ? *(const short8*)(fWB + (size_t)(c0 + m) * 8) : z8;
    f32x4 acc_f = mfma16(a, bf, f32x4{0.f, 0.f, 0.f, 0.f});

    const float sbv = sb[c0 + m], fbv = fb[c0 + m];
#pragma unroll
    for (int r = 0; r < 4; r++) {
        const int row = quad * 4 + r;
        sf[row][c0 + m]       = f2b(fmaxf(acc_s[r] + sbv, 0.f));   // zsf col 128+c0+m
        sf[row][128 + c0 + m] = f2b(fmaxf(acc_f[r] + fbv, 0.f));   // zsf col 256+c0+m
    }
    __syncthreads();

    // fusion: K=384
    f32x4 acc = f32x4{0.f, 0.f, 0.f, 0.f};
#pragma unroll
    for (int kt = 0; kt < 12; kt++) {
        const int k = kt * 32 + quad * 8;
        short8 av;
        if (kt < 4) av = *(const short8*)(zsfA + (size_t)(r0 + m) * 384 + k);
        else        av = *(const short8*)&sf[m][k - 128];
        short8 bv = *(const short8*)(Bt + (size_t)(c0 + m) * 384 + k);
        acc = mfma16(av, bv, acc);
    }
    const int col = c0 + m;
    const float bv = bias[col];
#pragma unroll
    for (int r = 0; r < 4; r++) {
        const int row = r0 + quad * 4 + r;
        const float v = fmaxf(acc[r] + bv, 0.f);
        hB[(size_t)row * 128 + col] = f2b(v);
        hF[(size_t)row * 128 + col] = v;
    }
}

// ---------------------------------------------------------------------------
// Hop GEMM + fused attention scalars. Block = 16 rows; wave w = head w
// (cols w*128..w*128+127). Epilogue: as_/ad_ dot in-register + 16-lane reduce.
// ---------------------------------------------------------------------------
__global__ __launch_bounds__(256) void gemmatt_kernel(
    const ushort* __restrict__ hB, const ushort* __restrict__ W,
    const float* __restrict__ asrc, const float* __restrict__ adst,
    ushort* __restrict__ xl, float* __restrict__ as_, float* __restrict__ ad_) {
    const int tid = threadIdx.x;
    const int lane = tid & 63, quad = lane >> 4, m = lane & 15;
    const int w = tid >> 6;
    const int r0 = blockIdx.x * 16;
    f32x4 acc[8];
#pragma unroll
    for (int ct = 0; ct < 8; ct++) acc[ct] = f32x4{0.f, 0.f, 0.f, 0.f};
#pragma unroll
    for (int kt = 0; kt < 4; kt++) {
        const int k = kt * 32 + quad * 8;
        short8 a = *(const short8*)(hB + (size_t)(r0 + m) * 128 + k);
#pragma unroll
        for (int ct = 0; ct < 8; ct++) {
            short8 bf = *(const short8*)(W + (size_t)(w * 128 + ct * 16 + m) * 128 + k);
            acc[ct] = mfma16(a, bf, acc[ct]);
        }
    }
    float sa[4] = {0.f, 0.f, 0.f, 0.f}, sd[4] = {0.f, 0.f, 0.f, 0.f};
#pragma unroll
    for (int ct = 0; ct < 8; ct++) {
        const int col = w * 128 + ct * 16 + m;
        const float av = asrc[col], dv = adst[col];
#pragma unroll
        for (int r = 0; r < 4; r++) {
            const float v = acc[ct][r];
            xl[(size_t)(r0 + quad * 4 + r) * 512 + col] = f2b(v);
            sa[r] = fmaf(v, av, sa[r]);
            sd[r] = fmaf(v, dv, sd[r]);
        }
    }
#pragma unroll
    for (int o = 1; o < 16; o <<= 1) {
#pragma unroll
        for (int r = 0; r < 4; r++) {
            sa[r] += __shfl_xor(sa[r], o);
            sd[r] += __shfl_xor(sd[r], o);
        }
    }
    if (m == 0) {
#pragma unroll
        for (int r = 0; r < 4; r++) {
            const int node = r0 + quad * 4 + r;
            as_[node * 4 + w] = sa[r];
            ad_[node * 4 + w] = sd[r];
        }
    }
}

// ---------------------------------------------------------------------------
// Per-(batch,edge,head) unnormalized softmax weight: exp(leaky(logit)).
// ---------------------------------------------------------------------------
__global__ __launch_bounds__(256) void edge_exp_kernel(
    const int* __restrict__ ei, const float* __restrict__ ew,
    const float* __restrict__ as_, const float* __restrict__ ad_,
    const float* __restrict__ se4, float* __restrict__ pexp) {
    const int idx = blockIdx.x * 256 + threadIdx.x;   // 131072
    const int b = idx >> 14, e = idx & (EE - 1);
    const int src = b * 1024 + ei[e];
    const int dst = b * 1024 + ei[EE + e];
    const float eaw = ew[e];
    const float4 s4 = *(const float4*)(as_ + src * 4);
    const float4 d4 = *(const float4*)(ad_ + dst * 4);
    float4 p;
    float* pp = (float*)&p;
    const float* s = (const float*)&s4;
    const float* d = (const float*)&d4;
#pragma unroll
    for (int h = 0; h < 4; h++) {
        float a = s[h] + d[h] + eaw * se4[h];
        a = (a < 0.f) ? 0.2f * a : a;
        pp[h] = EXP2(fminf(a, 60.f) * L2E);
    }
    *(float4*)(pexp + (size_t)idx * 4) = p;
}

// ---------------------------------------------------------------------------
// Fused GAT hop with 2-WAY EDGE-SLOT PARALLELISM: wave per (dst,batch).
// Lanes 0-31 (slot 0) process edges i=0,2,4..; lanes 32-63 (slot 1) process
// i=1,3,5.. — each half-wave covers all 128 channels at 4 cols/lane.
// Slot partials merged via shfl_xor(32); LN normalizes by 256 (cols counted
// twice); writeOut dot *0.5. [r8 form, best measured]
// ---------------------------------------------------------------------------
__global__ __launch_bounds__(256) void gat_kernel(
    float* __restrict__ hF, ushort* __restrict__ hB, const ushort* __restrict__ xl,
    const float* __restrict__ as_, const float* __restrict__ ad_,
    const float* __restrict__ pexp,
    const int* __restrict__ eidx, const int* __restrict__ offs,
    const int* __restrict__ deg0, const float* __restrict__ loopea,
    const int* __restrict__ ei,
    const float* __restrict__ se4, const float* __restrict__ bias,
    const float* __restrict__ lng, const float* __restrict__ lnb, int relu,
    int writeOut, const float* __restrict__ oW, const float* __restrict__ ob,
    float* __restrict__ out) {
    const int lane = threadIdx.x & 63;
    const int half = lane >> 5;                       // edge slot 0/1
    const int c0 = (lane & 31) * 2;                   // cols c0,c0+1,c0+64,c0+65
    const int v = blockIdx.x * 4 + (threadIdx.x >> 6);
    const int b = v >> 10, n = v & 1023;
    const int dg = deg0[n], off = offs[n];

    // self loop -> slot 0 only (slot 1 starts at zero)
    const float lea = loopea[n];
    const float4 s4 = *(const float4*)(as_ + v * 4);
    const float4 d4 = *(const float4*)(ad_ + v * 4);
    const float* sp = (const float*)&s4;
    const float* dp = (const float*)&d4;
    float den[4], num[4][4];
#pragma unroll
    for (int h = 0; h < 4; h++) {
        float a = sp[h] + dp[h] + lea * se4[h];
        a = (a < 0.f) ? 0.2f * a : a;
        float p = EXP2(fminf(a, 60.f) * L2E);
        if (half) p = 0.f;
        den[h] = p;
        const unsigned xa = *(const unsigned*)(xl + (size_t)v * 512 + h * 128 + c0);
        const unsigned xb = *(const unsigned*)(xl + (size_t)v * 512 + h * 128 + 64 + c0);
        num[h][0] = p * b2f_lo(xa);
        num[h][1] = p * b2f_hi(xa);
        num[h][2] = p * b2f_lo(xb);
        num[h][3] = p * b2f_hi(xb);
    }
    for (int i = half; i < dg; i += 2) {
        const int e = eidx[off + i];
        const int src = b * 1024 + ei[e];
        const float4 p4 = *(const float4*)(pexp + (size_t)(b * EE + e) * 4);
        const float* p = (const float*)&p4;
        const ushort* xr = xl + (size_t)src * 512 + c0;
#pragma unroll
        for (int h = 0; h < 4; h++) {
            const unsigned xa = *(const unsigned*)(xr + h * 128);
            const unsigned xb = *(const unsigned*)(xr + h * 128 + 64);
            den[h] += p[h];
            num[h][0] = fmaf(p[h], b2f_lo(xa), num[h][0]);
            num[h][1] = fmaf(p[h], b2f_hi(xa), num[h][1]);
            num[h][2] = fmaf(p[h], b2f_lo(xb), num[h][2]);
            num[h][3] = fmaf(p[h], b2f_hi(xb), num[h][3]);
        }
    }
    // merge edge slots (both halves end with identical sums)
#pragma unroll
    for (int h = 0; h < 4; h++) {
        den[h] += __shfl_xor(den[h], 32);
#pragma unroll
        for (int k = 0; k < 4; k++) num[h][k] += __shfl_xor(num[h][k], 32);
    }

    float o[4] = {0.f, 0.f, 0.f, 0.f};
#pragma unroll
    for (int h = 0; h < 4; h++) {
        const float inv = RCPF(den[h]);
#pragma unroll
        for (int k = 0; k < 4; k++) o[k] = fmaf(num[h][k], inv, o[k]);
    }

    const float2 bva = *(const float2*)(bias + c0);
    const float2 bvb = *(const float2*)(bias + 64 + c0);
    float d0 = o[0] * 0.25f + bva.x;
    float d1 = o[1] * 0.25f + bva.y;
    float d2 = o[2] * 0.25f + bvb.x;
    float d3 = o[3] * 0.25f + bvb.y;
    if (relu) {
        d0 = fmaxf(d0, 0.f); d1 = fmaxf(d1, 0.f);
        d2 = fmaxf(d2, 0.f); d3 = fmaxf(d3, 0.f);
    }
    const float2 hva = *(const float2*)(hF + (size_t)v * 128 + c0);
    const float2 hvb = *(const float2*)(hF + (size_t)v * 128 + 64 + c0);
    const float x0 = hva.x + d0, x1 = hva.y + d1;
    const float x2 = hvb.x + d2, x3 = hvb.y + d3;

    float s = (x0 + x1) + (x2 + x3);
#pragma unroll
    for (int o2 = 32; o2; o2 >>= 1) s += __shfl_xor(s, o2);
    const float mu = s * (1.f / 256.f);               // each col counted twice
    const float e0 = x0 - mu, e1 = x1 - mu, e2 = x2 - mu, e3 = x3 - mu;
    float vs = (e0 * e0 + e1 * e1) + (e2 * e2 + e3 * e3);
#pragma unroll
    for (int o2 = 32; o2; o2 >>= 1) vs += __shfl_xor(vs, o2);
    const float r = rsqrtf(vs * (1.f / 256.f) + 1e-5f);
    const float2 lga = *(const float2*)(lng + c0);
    const float2 lgb = *(const float2*)(lng + 64 + c0);
    const float2 lba = *(const float2*)(lnb + c0);
    const float2 lbb = *(const float2*)(lnb + 64 + c0);
    const float y0 = e0 * r * lga.x + lba.x;
    const float y1 = e1 * r * lga.y + lba.y;
    const float y2 = e2 * r * lgb.x + lbb.x;
    const float y3 = e3 * r * lgb.y + lbb.y;
    if (writeOut) {
        const float2 owa = *(const float2*)(oW + c0);
        const float2 owb = *(const float2*)(oW + 64 + c0);
        float t = (y0 * owa.x + y1 * owa.y) + (y2 * owb.x + y3 * owb.y);
#pragma unroll
        for (int o2 = 32; o2; o2 >>= 1) t += __shfl_xor(t, o2);
        if (lane == 0) out[v] = t * 0.5f + ob[0];     // cols counted twice
    } else if (half == 0) {
        *(float2*)(hF + (size_t)v * 128 + c0) = float2{y0, y1};
        *(float2*)(hF + (size_t)v * 128 + 64 + c0) = float2{y2, y3};
        const unsigned pka = (unsigned)f2b(y0) | ((unsigned)f2b(y1) << 16);
        const unsigned pkb = (unsigned)f2b(y2) | ((unsigned)f2b(y3) << 16);
        *(unsigned*)(hB + (size_t)v * 128 + c0) = pka;
        *(unsigned*)(hB + (size_t)v * 128 + 64 + c0) = pkb;
    }
}

// ---------------------------------------------------------------------------
extern "C" void kernel_launch(void* const* d_in, const int* in_sizes, int n_in,
                              void* d_out, int out_size, void* d_ws, size_t ws_size,
                              hipStream_t stream) {
    const float* dyn  = (const float*)d_in[0];
    const float* fcst = (const float*)d_in[1];
    const float* sta  = (const float*)d_in[2];
    const int*   ei   = (const int*)d_in[3];
    const float* ew   = (const float*)d_in[4];
    const float* lWih = (const float*)d_in[5];
    const float* lWhh = (const float*)d_in[6];
    const float* lbih = (const float*)d_in[7];
    const float* lbhh = (const float*)d_in[8];
    const float* sW = (const float*)d_in[9];
    const float* sb = (const float*)d_in[10];
    const float* fW = (const float*)d_in[11];
    const float* fb = (const float*)d_in[12];
    const float* uW = (const float*)d_in[13];
    const float* ub = (const float*)d_in[14];
    const float* g0W  = (const float*)d_in[15];
    const float* g0as = (const float*)d_in[16];
    const float* g0ad = (const float*)d_in[17];
    const float* g0ae = (const float*)d_in[18];
    const float* g0We = (const float*)d_in[19];
    const float* g0b  = (const float*)d_in[20];
    const float* g1W  = (const float*)d_in[21];
    const float* g1as = (const float*)d_in[22];
    const float* g1ad = (const float*)d_in[23];
    const float* g1ae = (const float*)d_in[24];
    const float* g1We = (const float*)d_in[25];
    const float* g1b  = (const float*)d_in[26];
    const float* ln0g = (const float*)d_in[27];
    const float* ln0b = (const float*)d_in[28];
    const float* ln1g = (const float*)d_in[29];
    const float* ln1b = (const float*)d_in[30];
    const float* oW = (const float*)d_in[31];
    const float* ob = (const float*)d_in[32];

    char* p = (char*)d_ws;
    ushort* castB = (ushort*)p; p += (size_t)O_END * 2 + 512;
    ushort* zsf = (ushort*)p;  p += (size_t)BN_ * 384 * 2;      // pexp overlays (dead after fusion)
    float*  hF  = (float*)p;   p += (size_t)BN_ * 128 * 4;
    ushort* hB  = (ushort*)p;  p += (size_t)BN_ * 128 * 2;
    ushort* xl  = (ushort*)p;  p += (size_t)BN_ * 512 * 2;
    float*  asb = (float*)p;   p += (size_t)BN_ * 4 * 4;
    float*  adb = (float*)p;   p += (size_t)BN_ * 4 * 4;
    int*    deg0   = (int*)p;   p += 4096;
    int*    offs   = (int*)p;   p += 4096;
    float*  loopea = (float*)p; p += 4096;
    int*    eidx   = (int*)p;   p += (size_t)EE * 4;
    float*  se     = (float*)p; p += 256;
    float*  pexp   = (float*)zsf;   // 8*16384*4 f32 = 2 MB, zsf dead after fusion

    const ushort* WihB = castB + O_WIH;
    const ushort* WhhB = castB + O_WHH;
    const ushort* staB = castB + O_STA;
    const ushort* fcsB = castB + O_FCS;
    const ushort* sWB  = castB + O_SW;
    const ushort* fWB  = castB + O_FW;
    const ushort* uWB  = castB + O_UW;
    const ushort* g0WB = castB + O_G0W;
    const ushort* g1WB = castB + O_G1W;

    cast_prep_kernel<<<1 + (O_END + 1023) / 1024, 1024, 0, stream>>>(
        lWih, lWhh, sta, fcst, sW, fW, uW, g0W, g1W, castB,
        ei, ew, g0We, g0ae, g1We, g1ae, deg0, offs, loopea, eidx, se);

    lstm_kernel<<<512, 256, 0, stream>>>(dyn, WihB, WhhB, lbih, lbhh, zsf);
    gemm_fusion_kernel<<<512, 512, 0, stream>>>(staB, sWB, sb, fcsB, fWB, fb,
                                                zsf, uWB, ub, hB, hF);

    // hop 0
    gemmatt_kernel<<<512, 256, 0, stream>>>(hB, g0WB, g0as, g0ad, xl, asb, adb);
    edge_exp_kernel<<<512, 256, 0, stream>>>(ei, ew, asb, adb, se, pexp);
    gat_kernel<<<2048, 256, 0, stream>>>(hF, hB, xl, asb, adb, pexp, eidx, offs, deg0,
                                         loopea, ei, se, g0b, ln0g, ln0b, 1,
                                         0, oW, ob, (float*)d_out);
    // hop 1
    gemmatt_kernel<<<512, 256, 0, stream>>>(hB, g1WB, g1as, g1ad, xl, asb, adb);
    edge_exp_kernel<<<512, 256, 0, stream>>>(ei, ew, asb, adb, se + 4, pexp);
    gat_kernel<<<2048, 256, 0, stream>>>(hF, hB, xl, asb, adb, pexp, eidx, offs, deg0,
                                         loopea, ei, se + 4, g1b, ln1g, ln1b, 0,
                                         1, oW, ob, (float*)d_out);
}

// Round 11
// 543.424 us; speedup vs baseline: 1.0616x; 1.0126x over previous
//
#include <hip/hip_runtime.h>
#include <hip/hip_bf16.h>
#include <stdint.h>

#define BB 8
#define TT 168
#define NN 1024
#define BN_ 8192
#define FD_ 16
#define EE 16384

typedef short short8 __attribute__((ext_vector_type(8)));
typedef __bf16 bf16x8 __attribute__((ext_vector_type(8)));
typedef float f32x4 __attribute__((ext_vector_type(4)));

#if __has_builtin(__builtin_amdgcn_exp2f)
#define EXP2(x) __builtin_amdgcn_exp2f(x)
#else
#define EXP2(x) exp2f(x)
#endif
#if __has_builtin(__builtin_amdgcn_rcpf)
#define RCPF(x) __builtin_amdgcn_rcpf(x)
#else
#define RCPF(x) (1.f / (x))
#endif
#define L2E 1.4426950408889634f
#define T2E 2.8853900817779268f

static __device__ __forceinline__ float b2f(ushort s) {
    unsigned u = ((unsigned)s) << 16;
    return __builtin_bit_cast(float, u);
}
static __device__ __forceinline__ ushort f2b(float f) {      // RNE
    unsigned u = __builtin_bit_cast(unsigned, f);
    unsigned lsb = (u >> 16) & 1u;
    u += 0x7fffu + lsb;
    return (ushort)(u >> 16);
}
static __device__ __forceinline__ ushort f2b_fast(float f) { // round-half-up, 2 ops
    unsigned u = __builtin_bit_cast(unsigned, f);
    return (ushort)((u + 0x8000u) >> 16);
}
static __device__ __forceinline__ f32x4 mfma16(short8 a, short8 b, f32x4 c) {
    return __builtin_amdgcn_mfma_f32_16x16x32_bf16(
        __builtin_bit_cast(bf16x8, a), __builtin_bit_cast(bf16x8, b), c, 0, 0, 0);
}

// ---------------------------------------------------------------------------
// Cast offsets (bf16 staging in ws).
// ---------------------------------------------------------------------------
#define O_WIH 0
#define O_WHH 8192
#define O_STA 73728
#define O_FCS 335872
#define O_SW  401408
#define O_FW  405504
#define O_UW  406528
#define O_G0W 455680
#define O_G1W 521216
#define O_END 586752

// ---------------------------------------------------------------------------
// Merged cast + graph-prep: block 0 (1024 thr) runs prep (degree/wsum LDS
// atomics, scan, CSR fill, self-loop ea, se); blocks 1.. cast f32->bf16.
// ---------------------------------------------------------------------------
__global__ __launch_bounds__(1024) void cast_prep_kernel(
    const float* __restrict__ Wih, const float* __restrict__ Whh,
    const float* __restrict__ sta, const float* __restrict__ fcst,
    const float* __restrict__ sW, const float* __restrict__ fW,
    const float* __restrict__ uW, const float* __restrict__ g0W,
    const float* __restrict__ g1W, ushort* __restrict__ dst,
    const int* __restrict__ ei, const float* __restrict__ ew,
    const float* __restrict__ We0, const float* __restrict__ ae0,
    const float* __restrict__ We1, const float* __restrict__ ae1,
    int* __restrict__ deg0, int* __restrict__ offs, float* __restrict__ loopea,
    int* __restrict__ eidx, float* __restrict__ se) {
    if (blockIdx.x != 0) {
        const int i = (blockIdx.x - 1) * 1024 + threadIdx.x;
        if (i >= O_END) return;
        float v;
        if      (i < O_WHH) v = Wih[i - O_WIH];
        else if (i < O_STA) v = Whh[i - O_WHH];
        else if (i < O_FCS) v = sta[i - O_STA];
        else if (i < O_SW)  v = fcst[i - O_FCS];
        else if (i < O_FW)  v = sW[i - O_SW];
        else if (i < O_UW)  v = fW[i - O_FW];
        else if (i < O_G0W) v = uW[i - O_UW];
        else if (i < O_G1W) v = g0W[i - O_G0W];
        else                v = g1W[i - O_G1W];
        dst[i] = f2b(v);
        return;
    }
    __shared__ int degL[1024];
    __shared__ float wsL[1024];
    __shared__ int sc[1024];
    __shared__ float seL[8];
    const int t = threadIdx.x;
    degL[t] = 0; wsL[t] = 0.f;
    if (t < 8) seL[t] = 0.f;
    __syncthreads();
    for (int e = t; e < EE; e += 1024) {
        const int d = ei[EE + e];
        atomicAdd(&degL[d], 1);
        atomicAdd(&wsL[d], ew[e]);
    }
    __syncthreads();
    const int d = degL[t];
    sc[t] = d;
    __syncthreads();
    for (int o = 1; o < 1024; o <<= 1) {
        const int v = (t >= o) ? sc[t - o] : 0;
        __syncthreads();
        sc[t] += v;
        __syncthreads();
    }
    const int excl = sc[t] - d;
    offs[t] = excl;
    deg0[t] = d;
    loopea[t] = wsL[t] / fmaxf((float)d, 1.f);
    degL[t] = excl;           // reuse as cursor
    __syncthreads();
    for (int e = t; e < EE; e += 1024) {
        const int dd = ei[EE + e];
        const int slot = atomicAdd(&degL[dd], 1);
        eidx[slot] = e;
    }
    // se: 8 groups (hop*4+head) x 128 elems
    const int g = t >> 7, k = t & 127;
    const int head = g & 3;
    const float* W = (g >> 2) ? We1 : We0;
    const float* A = (g >> 2) ? ae1 : ae0;
    atomicAdd(&seL[g], W[head * 128 + k] * A[head * 128 + k]);
    __syncthreads();
    if (t < 8) se[t] = seL[t];
}

// ---------------------------------------------------------------------------
// LSTM: 16 nodes/block, 512 blocks, 4 waves, double-buffered LDS ->
// ONE barrier per step. [r0 form, best measured 300.0 us — FROZEN.
// Closed lines (all measured worse/null): 8-wave occupancy 303, MFMA/trans
// interleave 387 (spills), anti-phase+setprio 308.6, merged-rcp 304.4.]
// ---------------------------------------------------------------------------
__global__ __launch_bounds__(256, 2) void lstm_kernel(
    const float* __restrict__ dyn,    // (B,T,N,16) f32
    const ushort* __restrict__ Wih,   // (512,16) bf16
    const ushort* __restrict__ Whh,   // (512,128) bf16
    const float* __restrict__ bih,
    const float* __restrict__ bhh,
    ushort* __restrict__ zsf)         // (8192,384) bf16, cols 0..127
{
    constexpr int HS = 168;           // [h(128) | x(16) | zero-pad(24)]
    __shared__ ushort hbuf[2][16 * HS];

    const int tid = threadIdx.x;
    const int blk = blockIdx.x;
    const int b = blk >> 6;
    const int n0 = (blk & 63) << 4;
    const int w = tid >> 6, lane = tid & 63, quad = lane >> 4, m = lane & 15;

    short8 Bf[5][4][2];
    float ci[2], cf[2], cg[2], co[2];
#pragma unroll
    for (int jj = 0; jj < 2; jj++) {
        const int u = (2 * w + jj) * 16 + m;
#pragma unroll
        for (int g = 0; g < 4; g++) {
            const int grow = g * 128 + u;
#pragma unroll
            for (int kt = 0; kt < 4; kt++)
                Bf[kt][g][jj] = *(const short8*)(Whh + grow * 128 + kt * 32 + quad * 8);
            if (quad < 2) Bf[4][g][jj] = *(const short8*)(Wih + grow * 16 + quad * 8);
            else          Bf[4][g][jj] = short8{0, 0, 0, 0, 0, 0, 0, 0};
        }
        ci[jj] = -L2E * (bih[u] + bhh[u]);
        cf[jj] = -L2E * (bih[128 + u] + bhh[128 + u]);
        cg[jj] =  T2E * (bih[256 + u] + bhh[256 + u]);
        co[jj] = -L2E * (bih[384 + u] + bhh[384 + u]);
    }

    float c[2][4];
#pragma unroll
    for (int jj = 0; jj < 2; jj++)
#pragma unroll
        for (int r = 0; r < 4; r++) c[jj][r] = 0.f;

    for (int i = tid; i < 2 * 16 * HS; i += 256) ((ushort*)hbuf)[i] = 0;
    __syncthreads();

    const int xn = tid >> 4, xf = tid & 15;
    const size_t xbase = (size_t)b * TT * NN * FD_ + (size_t)(n0 + xn) * FD_ + xf;
    hbuf[0][xn * HS + 128 + xf] = f2b(dyn[xbase]);         // x(0)
    float xv = dyn[xbase + (size_t)NN * FD_];              // x(1)
    __syncthreads();

    for (int t = 0; t < TT; t++) {
        const ushort* rb = hbuf[t & 1];
        ushort* wb = hbuf[(t + 1) & 1];
        if (t + 1 < TT) wb[xn * HS + 128 + xf] = f2b(xv);  // x(t+1) -> write buf
        if (t + 2 < TT) xv = dyn[xbase + (size_t)(t + 2) * NN * FD_];

        f32x4 acc[4][2];
#pragma unroll
        for (int g = 0; g < 4; g++)
#pragma unroll
            for (int jj = 0; jj < 2; jj++) acc[g][jj] = f32x4{0.f, 0.f, 0.f, 0.f};
#pragma unroll
        for (int kt = 0; kt < 5; kt++) {
            short8 a = *(const short8*)&rb[m * HS + kt * 32 + quad * 8];
#pragma unroll
            for (int g = 0; g < 4; g++)
#pragma unroll
                for (int jj = 0; jj < 2; jj++)
                    acc[g][jj] = mfma16(a, Bf[kt][g][jj], acc[g][jj]);
        }

#pragma unroll
        for (int jj = 0; jj < 2; jj++) {
            const int u = (2 * w + jj) * 16 + m;
#pragma unroll
            for (int r = 0; r < 4; r++) {
                const int n = quad * 4 + r;
                const float Di = 1.f + EXP2(fmaf(acc[0][jj][r], -L2E, ci[jj]));
                const float Df = 1.f + EXP2(fmaf(acc[1][jj][r], -L2E, cf[jj]));
                const float Eg = EXP2(fmaf(acc[2][jj][r], T2E, cg[jj]));
                const float Do = 1.f + EXP2(fmaf(acc[3][jj][r], -L2E, co[jj]));
                const float R  = RCPF(Di * (1.f + Eg));
                const float sf = RCPF(Df);
                const float cc = fmaf(sf, c[jj][r], (Eg - 1.f) * R);
                c[jj][r] = cc;
                const float Ec = EXP2(T2E * cc);
                const float h = (Ec - 1.f) * RCPF(Do * (1.f + Ec));
                wb[n * HS + u] = f2b_fast(h);
                if (t == TT - 1) zsf[(size_t)(blk * 16 + n) * 384 + u] = f2b_fast(h);
            }
        }
        __syncthreads();
    }
}

// ---------------------------------------------------------------------------
// Fused s/f + fusion GEMM: one 512-thr block per 16 rows. [r10 form]
// ---------------------------------------------------------------------------
__global__ __launch_bounds__(512) void gemm_fusion_kernel(
    const ushort* __restrict__ staB, const ushort* __restrict__ sWB,
    const float* __restrict__ sb,
    const ushort* __restrict__ fcsB, const ushort* __restrict__ fWB,
    const float* __restrict__ fb,
    const ushort* __restrict__ zsfA, const ushort* __restrict__ Bt,
    const float* __restrict__ bias, ushort* __restrict__ hB, float* __restrict__ hF) {
    constexpr int LP = 264;                    // padded LDS row (bf16)
    __shared__ ushort sf[16][LP];
    const int tid = threadIdx.x;
    const int lane = tid & 63, quad = lane >> 4, m = lane & 15;
    const int w = tid >> 6;
    const int r0 = blockIdx.x * 16, c0 = w * 16;
    const short8 z8 = short8{0, 0, 0, 0, 0, 0, 0, 0};

    // s: K=32
    short8 a = *(const short8*)(staB + (size_t)(r0 + m) * 32 + quad * 8);
    short8 bf = *(const short8*)(sWB + (size_t)(c0 + m) * 32 + quad * 8);
    f32x4 acc_s = mfma16(a, bf, f32x4{0.f, 0.f, 0.f, 0.f});
    // f: K=8 (quad 0 only)
    a  = (quad == 0) ? *(const short8*)(fcsB + (size_t)(r0 + m) * 8) : z8;
    bf = (quad == 0) ? *(const short8*)(fWB + (size_t)(c0 + m) * 8) : z8;
    f32x4 acc_f = mfma16(a, bf, f32x4{0.f, 0.f, 0.f, 0.f});

    const float sbv = sb[c0 + m], fbv = fb[c0 + m];
#pragma unroll
    for (int r = 0; r < 4; r++) {
        const int row = quad * 4 + r;
        sf[row][c0 + m]       = f2b(fmaxf(acc_s[r] + sbv, 0.f));   // zsf col 128+c0+m
        sf[row][128 + c0 + m] = f2b(fmaxf(acc_f[r] + fbv, 0.f));   // zsf col 256+c0+m
    }
    __syncthreads();

    // fusion: K=384
    f32x4 acc = f32x4{0.f, 0.f, 0.f, 0.f};
#pragma unroll
    for (int kt = 0; kt < 12; kt++) {
        const int k = kt * 32 + quad * 8;
        short8 av;
        if (kt < 4) av = *(const short8*)(zsfA + (size_t)(r0 + m) * 384 + k);
        else        av = *(const short8*)&sf[m][k - 128];
        short8 bv = *(const short8*)(Bt + (size_t)(c0 + m) * 384 + k);
        acc = mfma16(av, bv, acc);
    }
    const int col = c0 + m;
    const float bv = bias[col];
#pragma unroll
    for (int r = 0; r < 4; r++) {
        const int row = r0 + quad * 4 + r;
        const float v = fmaxf(acc[r] + bv, 0.f);
        hB[(size_t)row * 128 + col] = f2b(v);
        hF[(size_t)row * 128 + col] = v;
    }
}

// ---------------------------------------------------------------------------
// Hop GEMM + fused attention scalars. Block = 16 rows; wave w = head w
// (cols w*128..w*128+127). Epilogue: as_/ad_ dot in-register + 16-lane reduce.
// ---------------------------------------------------------------------------
__global__ __launch_bounds__(256) void gemmatt_kernel(
    const ushort* __restrict__ hB, const ushort* __restrict__ W,
    const float* __restrict__ asrc, const float* __restrict__ adst,
    ushort* __restrict__ xl, float* __restrict__ as_, float* __restrict__ ad_) {
    const int tid = threadIdx.x;
    const int lane = tid & 63, quad = lane >> 4, m = lane & 15;
    const int w = tid >> 6;
    const int r0 = blockIdx.x * 16;
    f32x4 acc[8];
#pragma unroll
    for (int ct = 0; ct < 8; ct++) acc[ct] = f32x4{0.f, 0.f, 0.f, 0.f};
#pragma unroll
    for (int kt = 0; kt < 4; kt++) {
        const int k = kt * 32 + quad * 8;
        short8 a = *(const short8*)(hB + (size_t)(r0 + m) * 128 + k);
#pragma unroll
        for (int ct = 0; ct < 8; ct++) {
            short8 bf = *(const short8*)(W + (size_t)(w * 128 + ct * 16 + m) * 128 + k);
            acc[ct] = mfma16(a, bf, acc[ct]);
        }
    }
    float sa[4] = {0.f, 0.f, 0.f, 0.f}, sd[4] = {0.f, 0.f, 0.f, 0.f};
#pragma unroll
    for (int ct = 0; ct < 8; ct++) {
        const int col = w * 128 + ct * 16 + m;
        const float av = asrc[col], dv = adst[col];
#pragma unroll
        for (int r = 0; r < 4; r++) {
            const float v = acc[ct][r];
            xl[(size_t)(r0 + quad * 4 + r) * 512 + col] = f2b(v);
            sa[r] = fmaf(v, av, sa[r]);
            sd[r] = fmaf(v, dv, sd[r]);
        }
    }
#pragma unroll
    for (int o = 1; o < 16; o <<= 1) {
#pragma unroll
        for (int r = 0; r < 4; r++) {
            sa[r] += __shfl_xor(sa[r], o);
            sd[r] += __shfl_xor(sd[r], o);
        }
    }
    if (m == 0) {
#pragma unroll
        for (int r = 0; r < 4; r++) {
            const int node = r0 + quad * 4 + r;
            as_[node * 4 + w] = sa[r];
            ad_[node * 4 + w] = sd[r];
        }
    }
}

// ---------------------------------------------------------------------------
// Per-(batch,edge,head) unnormalized softmax weight: exp(leaky(logit)).
// ---------------------------------------------------------------------------
__global__ __launch_bounds__(256) void edge_exp_kernel(
    const int* __restrict__ ei, const float* __restrict__ ew,
    const float* __restrict__ as_, const float* __restrict__ ad_,
    const float* __restrict__ se4, float* __restrict__ pexp) {
    const int idx = blockIdx.x * 256 + threadIdx.x;   // 131072
    const int b = idx >> 14, e = idx & (EE - 1);
    const int src = b * 1024 + ei[e];
    const int dst = b * 1024 + ei[EE + e];
    const float eaw = ew[e];
    const float4 s4 = *(const float4*)(as_ + src * 4);
    const float4 d4 = *(const float4*)(ad_ + dst * 4);
    float4 p;
    float* pp = (float*)&p;
    const float* s = (const float*)&s4;
    const float* d = (const float*)&d4;
#pragma unroll
    for (int h = 0; h < 4; h++) {
        float a = s[h] + d[h] + eaw * se4[h];
        a = (a < 0.f) ? 0.2f * a : a;
        pp[h] = EXP2(fminf(a, 60.f) * L2E);
    }
    *(float4*)(pexp + (size_t)idx * 4) = p;
}

// ---------------------------------------------------------------------------
// Fused GAT hop with 4-WAY EDGE-SLOT PARALLELISM: wave per (dst,batch).
// slot = lane>>4 processes edges i ≡ slot (mod 4); each lane owns 8
// CONSECUTIVE channels (c8 = (lane&15)*8), so each head's chunk is ONE
// b128 load (was 2x b32) — 4 loads/edge/lane, serial trips dg/4 (was dg/2).
// Slot merge = shfl_xor(16)+shfl_xor(32); LN counts each col 4x -> /512;
// writeOut dot *0.25; stores slot-0 only (2x float4 + uint4, vectorized).
// ---------------------------------------------------------------------------
__global__ __launch_bounds__(256) void gat_kernel(
    float* __restrict__ hF, ushort* __restrict__ hB, const ushort* __restrict__ xl,
    const float* __restrict__ as_, const float* __restrict__ ad_,
    const float* __restrict__ pexp,
    const int* __restrict__ eidx, const int* __restrict__ offs,
    const int* __restrict__ deg0, const float* __restrict__ loopea,
    const int* __restrict__ ei,
    const float* __restrict__ se4, const float* __restrict__ bias,
    const float* __restrict__ lng, const float* __restrict__ lnb, int relu,
    int writeOut, const float* __restrict__ oW, const float* __restrict__ ob,
    float* __restrict__ out) {
    const int lane = threadIdx.x & 63;
    const int slot = lane >> 4;                       // edge slot 0..3
    const int c8 = (lane & 15) * 8;                   // 8 consecutive channels
    const int v = blockIdx.x * 4 + (threadIdx.x >> 6);
    const int b = v >> 10, n = v & 1023;
    const int dg = deg0[n], off = offs[n];

    // self loop -> slot 0 only (other slots start at zero)
    const float lea = loopea[n];
    const float4 s4 = *(const float4*)(as_ + v * 4);
    const float4 d4 = *(const float4*)(ad_ + v * 4);
    const float* sp = (const float*)&s4;
    const float* dp = (const float*)&d4;
    float den[4], num[4][8];
#pragma unroll
    for (int h = 0; h < 4; h++) {
        float a = sp[h] + dp[h] + lea * se4[h];
        a = (a < 0.f) ? 0.2f * a : a;
        float p = EXP2(fminf(a, 60.f) * L2E);
        if (slot) p = 0.f;
        den[h] = p;
        const short8 x8 = *(const short8*)(xl + (size_t)v * 512 + h * 128 + c8);
#pragma unroll
        for (int k = 0; k < 8; k++) num[h][k] = p * b2f((ushort)x8[k]);
    }
    for (int i = slot; i < dg; i += 4) {
        const int e = eidx[off + i];
        const int src = b * 1024 + ei[e];
        const float4 p4 = *(const float4*)(pexp + (size_t)(b * EE + e) * 4);
        const float* p = (const float*)&p4;
        const ushort* xr = xl + (size_t)src * 512 + c8;
#pragma unroll
        for (int h = 0; h < 4; h++) {
            const short8 x8 = *(const short8*)(xr + h * 128);
            den[h] += p[h];
#pragma unroll
            for (int k = 0; k < 8; k++)
                num[h][k] = fmaf(p[h], b2f((ushort)x8[k]), num[h][k]);
        }
    }
    // merge 4 edge slots (all lanes end with full sums for their channels)
#pragma unroll
    for (int h = 0; h < 4; h++) {
        den[h] += __shfl_xor(den[h], 16);
        den[h] += __shfl_xor(den[h], 32);
#pragma unroll
        for (int k = 0; k < 8; k++) {
            num[h][k] += __shfl_xor(num[h][k], 16);
            num[h][k] += __shfl_xor(num[h][k], 32);
        }
    }

    float o[8] = {0.f, 0.f, 0.f, 0.f, 0.f, 0.f, 0.f, 0.f};
#pragma unroll
    for (int h = 0; h < 4; h++) {
        const float inv = RCPF(den[h]);
#pragma unroll
        for (int k = 0; k < 8; k++) o[k] = fmaf(num[h][k], inv, o[k]);
    }

    float x[8];
    {
        const float4 ba = *(const float4*)(bias + c8);
        const float4 bb = *(const float4*)(bias + c8 + 4);
        const float4 ha = *(const float4*)(hF + (size_t)v * 128 + c8);
        const float4 hb2 = *(const float4*)(hF + (size_t)v * 128 + c8 + 4);
        const float* bp = (const float*)&ba;
        const float* bq = (const float*)&bb;
        const float* hp = (const float*)&ha;
        const float* hq = (const float*)&hb2;
#pragma unroll
        for (int k = 0; k < 4; k++) {
            float dk = o[k] * 0.25f + bp[k];
            if (relu) dk = fmaxf(dk, 0.f);
            x[k] = hp[k] + dk;
            float dk2 = o[k + 4] * 0.25f + bq[k];
            if (relu) dk2 = fmaxf(dk2, 0.f);
            x[k + 4] = hq[k] + dk2;
        }
    }

    float s = ((x[0] + x[1]) + (x[2] + x[3])) + ((x[4] + x[5]) + (x[6] + x[7]));
#pragma unroll
    for (int o2 = 32; o2; o2 >>= 1) s += __shfl_xor(s, o2);
    const float mu = s * (1.f / 512.f);               // each col counted 4x
    float e[8];
    float vs = 0.f;
#pragma unroll
    for (int k = 0; k < 8; k++) { e[k] = x[k] - mu; vs += e[k] * e[k]; }
#pragma unroll
    for (int o2 = 32; o2; o2 >>= 1) vs += __shfl_xor(vs, o2);
    const float r = rsqrtf(vs * (1.f / 512.f) + 1e-5f);

    const float4 ga = *(const float4*)(lng + c8);
    const float4 gb = *(const float4*)(lng + c8 + 4);
    const float4 la = *(const float4*)(lnb + c8);
    const float4 lb = *(const float4*)(lnb + c8 + 4);
    const float* gp = (const float*)&ga;
    const float* gq = (const float*)&gb;
    const float* lp = (const float*)&la;
    const float* lq = (const float*)&lb;
    float y[8];
#pragma unroll
    for (int k = 0; k < 4; k++) {
        y[k]     = e[k] * r * gp[k] + lp[k];
        y[k + 4] = e[k + 4] * r * gq[k] + lq[k];
    }
    if (writeOut) {
        const float4 oa = *(const float4*)(oW + c8);
        const float4 ob4 = *(const float4*)(oW + c8 + 4);
        const float* op = (const float*)&oa;
        const float* oq = (const float*)&ob4;
        float t = 0.f;
#pragma unroll
        for (int k = 0; k < 4; k++) t += y[k] * op[k] + y[k + 4] * oq[k];
#pragma unroll
        for (int o2 = 32; o2; o2 >>= 1) t += __shfl_xor(t, o2);
        if (lane == 0) out[v] = t * 0.25f + ob[0];    // cols counted 4x
    } else if (slot == 0) {
        *(float4*)(hF + (size_t)v * 128 + c8) = float4{y[0], y[1], y[2], y[3]};
        *(float4*)(hF + (size_t)v * 128 + c8 + 4) = float4{y[4], y[5], y[6], y[7]};
        uint4 pk;
        pk.x = (unsigned)f2b(y[0]) | ((unsigned)f2b(y[1]) << 16);
        pk.y = (unsigned)f2b(y[2]) | ((unsigned)f2b(y[3]) << 16);
        pk.z = (unsigned)f2b(y[4]) | ((unsigned)f2b(y[5]) << 16);
        pk.w = (unsigned)f2b(y[6]) | ((unsigned)f2b(y[7]) << 16);
        *(uint4*)(hB + (size_t)v * 128 + c8) = pk;
    }
}

// ---------------------------------------------------------------------------
extern "C" void kernel_launch(void* const* d_in, const int* in_sizes, int n_in,
                              void* d_out, int out_size, void* d_ws, size_t ws_size,
                              hipStream_t stream) {
    const float* dyn  = (const float*)d_in[0];
    const float* fcst = (const float*)d_in[1];
    const float* sta  = (const float*)d_in[2];
    const int*   ei   = (const int*)d_in[3];
    const float* ew   = (const float*)d_in[4];
    const float* lWih = (const float*)d_in[5];
    const float* lWhh = (const float*)d_in[6];
    const float* lbih = (const float*)d_in[7];
    const float* lbhh = (const float*)d_in[8];
    const float* sW = (const float*)d_in[9];
    const float* sb = (const float*)d_in[10];
    const float* fW = (const float*)d_in[11];
    const float* fb = (const float*)d_in[12];
    const float* uW = (const float*)d_in[13];
    const float* ub = (const float*)d_in[14];
    const float* g0W  = (const float*)d_in[15];
    const float* g0as = (const float*)d_in[16];
    const float* g0ad = (const float*)d_in[17];
    const float* g0ae = (const float*)d_in[18];
    const float* g0We = (const float*)d_in[19];
    const float* g0b  = (const float*)d_in[20];
    const float* g1W  = (const float*)d_in[21];
    const float* g1as = (const float*)d_in[22];
    const float* g1ad = (const float*)d_in[23];
    const float* g1ae = (const float*)d_in[24];
    const float* g1We = (const float*)d_in[25];
    const float* g1b  = (const float*)d_in[26];
    const float* ln0g = (const float*)d_in[27];
    const float* ln0b = (const float*)d_in[28];
    const float* ln1g = (const float*)d_in[29];
    const float* ln1b = (const float*)d_in[30];
    const float* oW = (const float*)d_in[31];
    const float* ob = (const float*)d_in[32];

    char* p = (char*)d_ws;
    ushort* castB = (ushort*)p; p += (size_t)O_END * 2 + 512;
    ushort* zsf = (ushort*)p;  p += (size_t)BN_ * 384 * 2;      // pexp overlays (dead after fusion)
    float*  hF  = (float*)p;   p += (size_t)BN_ * 128 * 4;
    ushort* hB  = (ushort*)p;  p += (size_t)BN_ * 128 * 2;
    ushort* xl  = (ushort*)p;  p += (size_t)BN_ * 512 * 2;
    float*  asb = (float*)p;   p += (size_t)BN_ * 4 * 4;
    float*  adb = (float*)p;   p += (size_t)BN_ * 4 * 4;
    int*    deg0   = (int*)p;   p += 4096;
    int*    offs   = (int*)p;   p += 4096;
    float*  loopea = (float*)p; p += 4096;
    int*    eidx   = (int*)p;   p += (size_t)EE * 4;
    float*  se     = (float*)p; p += 256;
    float*  pexp   = (float*)zsf;   // 8*16384*4 f32 = 2 MB, zsf dead after fusion

    const ushort* WihB = castB + O_WIH;
    const ushort* WhhB = castB + O_WHH;
    const ushort* staB = castB + O_STA;
    const ushort* fcsB = castB + O_FCS;
    const ushort* sWB  = castB + O_SW;
    const ushort* fWB  = castB + O_FW;
    const ushort* uWB  = castB + O_UW;
    const ushort* g0WB = castB + O_G0W;
    const ushort* g1WB = castB + O_G1W;

    cast_prep_kernel<<<1 + (O_END + 1023) / 1024, 1024, 0, stream>>>(
        lWih, lWhh, sta, fcst, sW, fW, uW, g0W, g1W, castB,
        ei, ew, g0We, g0ae, g1We, g1ae, deg0, offs, loopea, eidx, se);

    lstm_kernel<<<512, 256, 0, stream>>>(dyn, WihB, WhhB, lbih, lbhh, zsf);
    gemm_fusion_kernel<<<512, 512, 0, stream>>>(staB, sWB, sb, fcsB, fWB, fb,
                                                zsf, uWB, ub, hB, hF);

    // hop 0
    gemmatt_kernel<<<512, 256, 0, stream>>>(hB, g0WB, g0as, g0ad, xl, asb, adb);
    edge_exp_kernel<<<512, 256, 0, stream>>>(ei, ew, asb, adb, se, pexp);
    gat_kernel<<<2048, 256, 0, stream>>>(hF, hB, xl, asb, adb, pexp, eidx, offs, deg0,
                                         loopea, ei, se, g0b, ln0g, ln0b, 1,
                                         0, oW, ob, (float*)d_out);
    // hop 1
    gemmatt_kernel<<<512, 256, 0, stream>>>(hB, g1WB, g1as, g1ad, xl, asb, adb);
    edge_exp_kernel<<<512, 256, 0, stream>>>(ei, ew, asb, adb, se + 4, pexp);
    gat_kernel<<<2048, 256, 0, stream>>>(hF, hB, xl, asb, adb, pexp, eidx, offs, deg0,
                                         loopea, ei, se + 4, g1b, ln1g, ln1b, 0,
                                         1, oW, ob, (float*)d_out);
}